// Round 10
// baseline (269.667 us; speedup 1.0000x reference)
//
#include <hip/hip_runtime.h>
#include <math.h>

#define D_MODEL 512
#define N_HEADS 8
#define DK 64
#define QSCALE (0.0625f * 1.44269504089f)

typedef __attribute__((ext_vector_type(8))) short short8;
typedef __attribute__((ext_vector_type(4))) float f32x4;
typedef __attribute__((ext_vector_type(16))) float f32x16;

typedef __attribute__((address_space(1))) const unsigned as1_uint;
typedef __attribute__((address_space(3))) unsigned as3_uint;

__device__ __forceinline__ unsigned short f2bf(float f) {
    unsigned u = __builtin_bit_cast(unsigned, f);
    u = (u + 0x7fff + ((u >> 16) & 1)) >> 16;   // RNE
    return (unsigned short)u;
}

// ---------------- x fp32 -> bf16 ----------------
__global__ __launch_bounds__(256) void cvt_x_kernel(const float* __restrict__ x,
                                                    unsigned short* __restrict__ xb, int n8)
{
    int i = blockIdx.x * 256 + threadIdx.x;
    if (i >= n8) return;
    float4 a = ((const float4*)x)[i * 2];
    float4 b = ((const float4*)x)[i * 2 + 1];
    short8 o;
    o[0] = f2bf(a.x); o[1] = f2bf(a.y); o[2] = f2bf(a.z); o[3] = f2bf(a.w);
    o[4] = f2bf(b.x); o[5] = f2bf(b.y); o[6] = f2bf(b.z); o[7] = f2bf(b.w);
    ((short8*)xb)[i] = o;
}

// ---------------- mask fp32 {0,0.5,1} -> u8 {0,1,2} ----------------
__global__ __launch_bounds__(256) void cvt_mask_kernel(const float* __restrict__ m,
                                                       unsigned char* __restrict__ mu, int n4)
{
    int i = blockIdx.x * 256 + threadIdx.x;
    if (i >= n4) return;
    float4 v = ((const float4*)m)[i];
    uchar4 o = { (unsigned char)(v.x * 2.0f + 0.5f),
                 (unsigned char)(v.y * 2.0f + 0.5f),
                 (unsigned char)(v.z * 2.0f + 0.5f),
                 (unsigned char)(v.w * 2.0f + 0.5f) };
    ((uchar4*)mu)[i] = o;
}

// ---------------- W [K][N] fp32 -> Wt [N][K] bf16 ----------------
__global__ __launch_bounds__(256) void cvt_wt_kernel(const float* __restrict__ W,
                                                     unsigned short* __restrict__ Wt)
{
    __shared__ float tile[64][65];
    int t = threadIdx.x;
    int c0 = blockIdx.x * 64;   // n
    int r0 = blockIdx.y * 64;   // k
    #pragma unroll
    for (int i = 0; i < 16; i++) {
        int e = i * 256 + t, r = e >> 6, c = e & 63;
        tile[c][r] = W[(size_t)(r0 + r) * D_MODEL + c0 + c];
    }
    __syncthreads();
    #pragma unroll
    for (int i = 0; i < 16; i++) {
        int e = i * 256 + t, n = e >> 6, kk = e & 63;
        Wt[(size_t)(c0 + n) * D_MODEL + r0 + kk] = f2bf(tile[n][kk]);
    }
}

// ---------------- fused QKV GEMM: [q|k|v] = x @ [Wq|Wk|Wv] + b ----------------
__global__ __launch_bounds__(512) void gemm_qkv_kernel(
    const unsigned short* __restrict__ A, const unsigned short* __restrict__ Wt,
    const float* __restrict__ bq, const float* __restrict__ bk, const float* __restrict__ bv,
    unsigned short* __restrict__ qb, unsigned short* __restrict__ kb,
    unsigned short* __restrict__ vb, int M, int T)
{
    constexpr int K = D_MODEL;
    __shared__ unsigned short As[2][128 * 32];
    __shared__ unsigned short Bs[2][128 * 32];
    int t = threadIdx.x;
    int lane = t & 63, w = t >> 6;
    int ql = lane & 15, kg = lane >> 4;
    int m0 = blockIdx.y * 128, n0 = blockIdx.x * 128;
    int wm = w >> 2, wn = w & 3;
    bool vmode = (n0 >= 1024);

    const unsigned short* srcA = A + (size_t)(m0 + (t >> 2)) * K + (t & 3) * 8;
    const unsigned short* srcB = Wt + (size_t)(n0 + (t >> 2)) * K + (t & 3) * 8;

    f32x4 acc[4][2];
    #pragma unroll
    for (int i = 0; i < 4; i++)
        #pragma unroll
        for (int j = 0; j < 2; j++) { f32x4 z = {0.f, 0.f, 0.f, 0.f}; acc[i][j] = z; }

    constexpr int NIT = K / 32;
    int cur = 0;
    __builtin_amdgcn_global_load_lds((as1_uint*)(srcA),
        (as3_uint*)((char*)&As[0][0] + w * 1024), 16, 0, 0);
    __builtin_amdgcn_global_load_lds((as1_uint*)(srcB),
        (as3_uint*)((char*)&Bs[0][0] + w * 1024), 16, 0, 0);
    __syncthreads();

    for (int it = 0; it < NIT; ++it) {
        if (it + 1 < NIT) {
            int k0 = (it + 1) * 32;
            __builtin_amdgcn_global_load_lds((as1_uint*)(srcA + k0),
                (as3_uint*)((char*)&As[cur ^ 1][0] + w * 1024), 16, 0, 0);
            __builtin_amdgcn_global_load_lds((as1_uint*)(srcB + k0),
                (as3_uint*)((char*)&Bs[cur ^ 1][0] + w * 1024), 16, 0, 0);
        }
        short8 af[4], bfr[2];
        #pragma unroll
        for (int fm = 0; fm < 4; fm++)
            af[fm] = *(const short8*)((const char*)&As[cur][0] + (wm * 64 + fm * 16 + ql) * 64 + kg * 16);
        #pragma unroll
        for (int fn = 0; fn < 2; fn++)
            bfr[fn] = *(const short8*)((const char*)&Bs[cur][0] + (wn * 32 + fn * 16 + ql) * 64 + kg * 16);
        if (vmode) {
            #pragma unroll
            for (int fm = 0; fm < 4; fm++)
                #pragma unroll
                for (int fn = 0; fn < 2; fn++)
                    acc[fm][fn] = __builtin_amdgcn_mfma_f32_16x16x32_bf16(bfr[fn], af[fm], acc[fm][fn], 0, 0, 0);
        } else {
            #pragma unroll
            for (int fm = 0; fm < 4; fm++)
                #pragma unroll
                for (int fn = 0; fn < 2; fn++)
                    acc[fm][fn] = __builtin_amdgcn_mfma_f32_16x16x32_bf16(af[fm], bfr[fn], acc[fm][fn], 0, 0, 0);
        }
        __syncthreads();
        cur ^= 1;
    }

    #pragma unroll
    for (int fm = 0; fm < 4; fm++) {
        #pragma unroll
        for (int fn = 0; fn < 2; fn++) {
            if (vmode) {
                int m = m0 + wm * 64 + fm * 16 + ql;
                int b = m / T, tt = m % T;
                #pragma unroll
                for (int r = 0; r < 4; r++) {
                    int n = (n0 - 1024) + wn * 32 + fn * 16 + kg * 4 + r;
                    float val = acc[fm][fn][r] + bv[n];
                    int h = n >> 6, d = n & 63;
                    vb[((size_t)(b * N_HEADS + h) * DK + d) * T + tt] = f2bf(val);
                }
            } else {
                int n = n0 + wn * 32 + fn * 16 + ql;
                int nn = n & 511;
                bool isq = (n0 < 512);
                float bn = isq ? bq[nn] : bk[nn];
                unsigned short* dst = isq ? qb : kb;
                int h = nn >> 6, d = nn & 63;
                #pragma unroll
                for (int r = 0; r < 4; r++) {
                    int m = m0 + wm * 64 + fm * 16 + kg * 4 + r;
                    int b = m / T, tt = m % T;
                    float val = acc[fm][fn][r] + bn;
                    if (isq) val *= QSCALE;
                    dst[((size_t)(b * N_HEADS + h) * T + tt) * DK + d] = f2bf(val);
                }
            }
        }
    }
}

// ---------------- out-proj GEMM: fp32 out = attb @ Wo + bo ----------------
__global__ __launch_bounds__(512) void gemm_out_kernel(
    const unsigned short* __restrict__ A, const unsigned short* __restrict__ Bt,
    const float* __restrict__ bias, float* __restrict__ outp, int M)
{
    constexpr int K = D_MODEL;
    __shared__ unsigned short As[2][128 * 32];
    __shared__ unsigned short Bs[2][128 * 32];
    int t = threadIdx.x;
    int lane = t & 63, w = t >> 6;
    int ql = lane & 15, kg = lane >> 4;
    int m0 = blockIdx.y * 128, n0 = blockIdx.x * 128;
    int wm = w >> 2, wn = w & 3;

    const unsigned short* srcA = A + (size_t)(m0 + (t >> 2)) * K + (t & 3) * 8;
    const unsigned short* srcB = Bt + (size_t)(n0 + (t >> 2)) * K + (t & 3) * 8;

    f32x4 acc[4][2];
    #pragma unroll
    for (int i = 0; i < 4; i++)
        #pragma unroll
        for (int j = 0; j < 2; j++) { f32x4 z = {0.f, 0.f, 0.f, 0.f}; acc[i][j] = z; }

    constexpr int NIT = K / 32;
    int cur = 0;
    __builtin_amdgcn_global_load_lds((as1_uint*)(srcA),
        (as3_uint*)((char*)&As[0][0] + w * 1024), 16, 0, 0);
    __builtin_amdgcn_global_load_lds((as1_uint*)(srcB),
        (as3_uint*)((char*)&Bs[0][0] + w * 1024), 16, 0, 0);
    __syncthreads();

    for (int it = 0; it < NIT; ++it) {
        if (it + 1 < NIT) {
            int k0 = (it + 1) * 32;
            __builtin_amdgcn_global_load_lds((as1_uint*)(srcA + k0),
                (as3_uint*)((char*)&As[cur ^ 1][0] + w * 1024), 16, 0, 0);
            __builtin_amdgcn_global_load_lds((as1_uint*)(srcB + k0),
                (as3_uint*)((char*)&Bs[cur ^ 1][0] + w * 1024), 16, 0, 0);
        }
        short8 af[4], bfr[2];
        #pragma unroll
        for (int fm = 0; fm < 4; fm++)
            af[fm] = *(const short8*)((const char*)&As[cur][0] + (wm * 64 + fm * 16 + ql) * 64 + kg * 16);
        #pragma unroll
        for (int fn = 0; fn < 2; fn++)
            bfr[fn] = *(const short8*)((const char*)&Bs[cur][0] + (wn * 32 + fn * 16 + ql) * 64 + kg * 16);
        #pragma unroll
        for (int fm = 0; fm < 4; fm++)
            #pragma unroll
            for (int fn = 0; fn < 2; fn++)
                acc[fm][fn] = __builtin_amdgcn_mfma_f32_16x16x32_bf16(af[fm], bfr[fn], acc[fm][fn], 0, 0, 0);
        __syncthreads();
        cur ^= 1;
    }

    #pragma unroll
    for (int fm = 0; fm < 4; fm++) {
        #pragma unroll
        for (int fn = 0; fn < 2; fn++) {
            int n = n0 + wn * 32 + fn * 16 + ql;
            float bn = bias[n];
            #pragma unroll
            for (int r = 0; r < 4; r++) {
                int m = m0 + wm * 64 + fm * 16 + kg * 4 + r;
                outp[(size_t)m * D_MODEL + n] = acc[fm][fn][r] + bn;
            }
        }
    }
}

// ---------------- MFMA flash attention v10: 2-wave blocks, 4 barrier domains/CU ----------------
// Same 32x32x16 in-register-P math as v9; block = 2 waves (QB=64), grid (16, T/64).
// LDS 32KB/block (K,V dbuf only) -> 4 blocks/CU resident = 4 independent barrier domains.
__global__ __launch_bounds__(128) void attn_mfma_kernel(
    const unsigned short* __restrict__ q, const unsigned short* __restrict__ k,
    const unsigned short* __restrict__ v, const unsigned char* __restrict__ mu,
    unsigned short* __restrict__ out, int B, int T)
{
    __shared__ unsigned short Ks[2][64 * 64];
    __shared__ unsigned short Vt[2][64 * 64];

    int t = threadIdx.x;
    int lane = t & 63, w = t >> 6;          // w in {0,1}
    int ln = lane & 31, hi = lane >> 5;
    int bh = blockIdx.x;
    int qt = blockIdx.y;
    int hh = bh & (N_HEADS - 1), b = bh >> 3;
    int qr0 = qt * 64;

    const char* kbase = (const char*)(k + (size_t)bh * T * DK);
    const char* vbase = (const char*)(v + (size_t)bh * DK * T);

    // staging: 128 threads x 4 chunks x 16B = 8KB per buffer (K and V each)
    const char* gK[4];
    const char* gV[4];
    int linv[4];
    #pragma unroll
    for (int i = 0; i < 4; i++) {
        int lin = i * 2048 + t * 16;
        linv[i] = lin;
        int row = lin >> 7;
        int sw = (row & 7) << 4;
        gK[i] = kbase + (size_t)row * 128 + ((lin & 127) ^ sw);
        gV[i] = vbase + (size_t)row * (2 * T) + ((lin & 127) ^ sw);
    }

    // Q B-fragments: lane holds Q[q = qr0 + w*32 + ln][ks*16 + hi*8 .. +7]
    short8 qfr[4];
    {
        const unsigned short* qrow = q + ((size_t)bh * T + qr0 + w * 32 + ln) * DK + hi * 8;
        #pragma unroll
        for (int ks = 0; ks < 4; ks++)
            qfr[ks] = *(const short8*)(qrow + ks * 16);
    }

    // mask: lane's q-row, strided dwords (kcol = rb*32 + g*8 + 4*hi + 0..3)
    const unsigned char* mbase = mu + (size_t)(qr0 + w * 32 + ln) * T + 4 * hi;

    f32x16 oacc[2];
    #pragma unroll
    for (int db = 0; db < 2; db++)
        #pragma unroll
        for (int i = 0; i < 16; i++) oacc[db][i] = 0.f;
    float lacc = 0.f;

    // prologue: mask tile 0 + stage K/V tile 0 -> buf 0
    unsigned mcur[8];
    #pragma unroll
    for (int rb = 0; rb < 2; rb++)
        #pragma unroll
        for (int g = 0; g < 4; g++)
            mcur[rb * 4 + g] = *(const unsigned*)(mbase + rb * 32 + g * 8);
    #pragma unroll
    for (int i = 0; i < 4; i++) {
        __builtin_amdgcn_global_load_lds((as1_uint*)gK[i],
            (as3_uint*)((char*)&Ks[0][0] + linv[i]), 16, 0, 0);
        __builtin_amdgcn_global_load_lds((as1_uint*)gV[i],
            (as3_uint*)((char*)&Vt[0][0] + linv[i]), 16, 0, 0);
    }

    int ntiles = T / 64;
    for (int kt = 0; kt < ntiles; kt++) {
        __syncthreads();   // buf[cur] staged (vmcnt drained); prev reads done
        int cur = kt & 1;
        bool havenext = (kt + 1) < ntiles;

        unsigned mnxt[8];
        if (havenext) {
            const unsigned char* mp = mbase + (size_t)(kt + 1) * 64;
            #pragma unroll
            for (int rb = 0; rb < 2; rb++)
                #pragma unroll
                for (int g = 0; g < 4; g++)
                    mnxt[rb * 4 + g] = *(const unsigned*)(mp + rb * 32 + g * 8);
            size_t ko = (size_t)(kt + 1) * 8192;
            size_t vo = (size_t)(kt + 1) * 128;
            #pragma unroll
            for (int i = 0; i < 4; i++) {
                __builtin_amdgcn_global_load_lds((as1_uint*)(gK[i] + ko),
                    (as3_uint*)((char*)&Ks[cur ^ 1][0] + linv[i]), 16, 0, 0);
                __builtin_amdgcn_global_load_lds((as1_uint*)(gV[i] + vo),
                    (as3_uint*)((char*)&Vt[cur ^ 1][0] + linv[i]), 16, 0, 0);
            }
        }

        // QK^T (swapped): sacc[rb][reg] = S[kcol = rb*32 + (reg&3)+8*(reg>>2)+4*hi][q = ln]
        f32x16 sacc[2];
        #pragma unroll
        for (int rb = 0; rb < 2; rb++)
            #pragma unroll
            for (int i = 0; i < 16; i++) sacc[rb][i] = 0.f;
        __builtin_amdgcn_s_setprio(1);
        #pragma unroll
        for (int ks = 0; ks < 4; ks++) {
            #pragma unroll
            for (int rb = 0; rb < 2; rb++) {
                int row = rb * 32 + ln;
                short8 kf = *(const short8*)((const char*)&Ks[cur][0] +
                            ((row * 128 + ks * 32 + hi * 16) ^ ((row & 7) << 4)));
                sacc[rb] = __builtin_amdgcn_mfma_f32_32x32x16_bf16(kf, qfr[ks], sacc[rb], 0, 0, 0);
            }
        }
        __builtin_amdgcn_s_setprio(0);

        // softmax: p = exp2(s*m); build PV A-frags in-register (cvt_pk + permlane32_swap)
        short8 pa[4];
        #pragma unroll
        for (int rb = 0; rb < 2; rb++) {
            float p[16];
            #pragma unroll
            for (int g = 0; g < 4; g++) {
                unsigned mw = mcur[rb * 4 + g];
                float p0 = __builtin_amdgcn_exp2f(sacc[rb][g * 4 + 0] * (float)(mw & 0xffu));
                float p1 = __builtin_amdgcn_exp2f(sacc[rb][g * 4 + 1] * (float)((mw >> 8) & 0xffu));
                float p2 = __builtin_amdgcn_exp2f(sacc[rb][g * 4 + 2] * (float)((mw >> 16) & 0xffu));
                float p3 = __builtin_amdgcn_exp2f(sacc[rb][g * 4 + 3] * (float)(mw >> 24));
                p[g * 4 + 0] = p0; p[g * 4 + 1] = p1; p[g * 4 + 2] = p2; p[g * 4 + 3] = p3;
                lacc += (p0 + p1) + (p2 + p3);
            }
            #pragma unroll
            for (int kl = 0; kl < 2; kl++) {
                int b0 = kl * 8;
                unsigned d0, d1, d2, d3;
                asm("v_cvt_pk_bf16_f32 %0, %1, %2" : "=v"(d0) : "v"(p[b0 + 0]), "v"(p[b0 + 1]));
                asm("v_cvt_pk_bf16_f32 %0, %1, %2" : "=v"(d1) : "v"(p[b0 + 2]), "v"(p[b0 + 3]));
                asm("v_cvt_pk_bf16_f32 %0, %1, %2" : "=v"(d2) : "v"(p[b0 + 4]), "v"(p[b0 + 5]));
                asm("v_cvt_pk_bf16_f32 %0, %1, %2" : "=v"(d3) : "v"(p[b0 + 6]), "v"(p[b0 + 7]));
                asm("v_permlane32_swap_b32 %0, %1" : "+v"(d0), "+v"(d2));
                asm("v_permlane32_swap_b32 %0, %1" : "+v"(d1), "+v"(d3));
                uint4 fr = { d0, d1, d2, d3 };
                pa[rb * 2 + kl] = __builtin_bit_cast(short8, fr);
            }
        }

        // PV: oacc[db] += P(32q x 64k) @ V(64k x [db*32..+31])
        __builtin_amdgcn_s_setprio(1);
        #pragma unroll
        for (int ks = 0; ks < 4; ks++) {
            #pragma unroll
            for (int db = 0; db < 2; db++) {
                int row = db * 32 + ln;
                short8 vb = *(const short8*)((const char*)&Vt[cur][0] +
                            ((row * 128 + ks * 32 + hi * 16) ^ ((row & 7) << 4)));
                oacc[db] = __builtin_amdgcn_mfma_f32_32x32x16_bf16(pa[ks], vb, oacc[db], 0, 0, 0);
            }
        }
        __builtin_amdgcn_s_setprio(0);

        if (havenext) {
            #pragma unroll
            for (int c = 0; c < 8; c++) mcur[c] = mnxt[c];
        }
    }

    // l: lane owns q=ln; other half of kcols sits at lane^32
    lacc += __shfl_xor(lacc, 32, 64);

    // store: oacc[db][reg] is O[q = (reg&3)+8*(reg>>2)+4*hi][d = db*32 + ln]
    #pragma unroll
    for (int reg = 0; reg < 16; reg++) {
        int qoff = (reg & 3) + 8 * (reg >> 2) + 4 * hi;
        float linv = 1.0f / __shfl(lacc, qoff, 64);
        size_t rowo = ((size_t)b * T + qr0 + w * 32 + qoff) * D_MODEL + hh * DK + ln;
        out[rowo]      = f2bf(oacc[0][reg] * linv);
        out[rowo + 32] = f2bf(oacc[1][reg] * linv);
    }
}

extern "C" void kernel_launch(void* const* d_in, const int* in_sizes, int n_in,
                              void* d_out, int out_size, void* d_ws, size_t ws_size,
                              hipStream_t stream) {
    const float* x    = (const float*)d_in[0];
    const float* mask = (const float*)d_in[1];
    const float* Wq   = (const float*)d_in[2];
    const float* bq   = (const float*)d_in[3];
    const float* Wk   = (const float*)d_in[4];
    const float* bk   = (const float*)d_in[5];
    const float* Wv   = (const float*)d_in[6];
    const float* bv   = (const float*)d_in[7];
    const float* Wo   = (const float*)d_in[8];
    const float* bo   = (const float*)d_in[9];

    int T = (int)(sqrt((double)in_sizes[1]) + 0.5);   // 4096
    int C = D_MODEL;
    int B = in_sizes[0] / (T * C);                    // 2
    int M = B * T;

    size_t MK = (size_t)M * C;
    unsigned short* xb  = (unsigned short*)d_ws;
    unsigned short* Wtq = xb + MK;                    // [1536][512] contiguous
    unsigned short* Wtk = Wtq + (size_t)C * C;
    unsigned short* Wtv = Wtk + (size_t)C * C;
    unsigned short* Wto = Wtv + (size_t)C * C;
    unsigned short* qb  = Wto + (size_t)C * C;
    unsigned short* kb  = qb + MK;
    unsigned short* vb  = kb + MK;
    unsigned short* attb = vb + MK;
    unsigned char*  mu  = (unsigned char*)(attb + MK);

    int n8 = (int)(MK / 8);
    cvt_x_kernel<<<(n8 + 255) / 256, 256, 0, stream>>>(x, xb, n8);
    int n4 = T * T / 4;
    cvt_mask_kernel<<<(n4 + 255) / 256, 256, 0, stream>>>(mask, mu, n4);
    dim3 wtg(C / 64, C / 64, 1);
    cvt_wt_kernel<<<wtg, 256, 0, stream>>>(Wq, Wtq);
    cvt_wt_kernel<<<wtg, 256, 0, stream>>>(Wk, Wtk);
    cvt_wt_kernel<<<wtg, 256, 0, stream>>>(Wv, Wtv);
    cvt_wt_kernel<<<wtg, 256, 0, stream>>>(Wo, Wto);

    dim3 gq(3 * C / 128, M / 128, 1);
    gemm_qkv_kernel<<<gq, 512, 0, stream>>>(xb, Wtq, bq, bk, bv, qb, kb, vb, M, T);

    dim3 ga(B * N_HEADS, T / 64, 1);
    attn_mfma_kernel<<<ga, 128, 0, stream>>>(qb, kb, vb, mu, attb, B, T);

    dim3 gg(C / 128, M / 128, 1);
    gemm_out_kernel<<<gg, 512, 0, stream>>>(attb, Wto, bo, (float*)d_out, M);
}

// Round 11
// 217.241 us; speedup vs baseline: 1.2413x; 1.2413x over previous
//
#include <hip/hip_runtime.h>
#include <math.h>

#define D_MODEL 512
#define N_HEADS 8
#define DK 64
#define QSCALE (0.0625f * 1.44269504089f)

typedef __attribute__((ext_vector_type(8))) short short8;
typedef __attribute__((ext_vector_type(4))) float f32x4;
typedef __attribute__((ext_vector_type(16))) float f32x16;

typedef __attribute__((address_space(1))) const unsigned as1_uint;
typedef __attribute__((address_space(3))) unsigned as3_uint;

__device__ __forceinline__ unsigned short f2bf(float f) {
    unsigned u = __builtin_bit_cast(unsigned, f);
    u = (u + 0x7fff + ((u >> 16) & 1)) >> 16;   // RNE
    return (unsigned short)u;
}

// ---------------- x fp32 -> bf16 ----------------
__global__ __launch_bounds__(256) void cvt_x_kernel(const float* __restrict__ x,
                                                    unsigned short* __restrict__ xb, int n8)
{
    int i = blockIdx.x * 256 + threadIdx.x;
    if (i >= n8) return;
    float4 a = ((const float4*)x)[i * 2];
    float4 b = ((const float4*)x)[i * 2 + 1];
    short8 o;
    o[0] = f2bf(a.x); o[1] = f2bf(a.y); o[2] = f2bf(a.z); o[3] = f2bf(a.w);
    o[4] = f2bf(b.x); o[5] = f2bf(b.y); o[6] = f2bf(b.z); o[7] = f2bf(b.w);
    ((short8*)xb)[i] = o;
}

// ---------------- mask fp32 {0,0.5,1} -> u8 {0,1,2} ----------------
__global__ __launch_bounds__(256) void cvt_mask_kernel(const float* __restrict__ m,
                                                       unsigned char* __restrict__ mu, int n4)
{
    int i = blockIdx.x * 256 + threadIdx.x;
    if (i >= n4) return;
    float4 v = ((const float4*)m)[i];
    uchar4 o = { (unsigned char)(v.x * 2.0f + 0.5f),
                 (unsigned char)(v.y * 2.0f + 0.5f),
                 (unsigned char)(v.z * 2.0f + 0.5f),
                 (unsigned char)(v.w * 2.0f + 0.5f) };
    ((uchar4*)mu)[i] = o;
}

// ---------------- W [K][N] fp32 -> Wt [N][K] bf16 (all 4 in one launch) ----------------
__global__ __launch_bounds__(256) void cvt_wt4_kernel(
    const float* __restrict__ Wq, const float* __restrict__ Wk,
    const float* __restrict__ Wv, const float* __restrict__ Wo,
    unsigned short* __restrict__ Wt)
{
    __shared__ float tile[64][65];
    int z = blockIdx.z;
    const float* W = (z == 0) ? Wq : (z == 1) ? Wk : (z == 2) ? Wv : Wo;
    unsigned short* dst = Wt + (size_t)z * D_MODEL * D_MODEL;
    int t = threadIdx.x;
    int c0 = blockIdx.x * 64;   // n
    int r0 = blockIdx.y * 64;   // k
    #pragma unroll
    for (int i = 0; i < 16; i++) {
        int e = i * 256 + t, r = e >> 6, c = e & 63;
        tile[c][r] = W[(size_t)(r0 + r) * D_MODEL + c0 + c];
    }
    __syncthreads();
    #pragma unroll
    for (int i = 0; i < 16; i++) {
        int e = i * 256 + t, n = e >> 6, kk = e & 63;
        dst[(size_t)(c0 + n) * D_MODEL + r0 + kk] = f2bf(tile[n][kk]);
    }
}

// ---------------- fused QKV GEMM: [q|k|v] = x @ [Wq|Wk|Wv] + b ----------------
__global__ __launch_bounds__(512) void gemm_qkv_kernel(
    const unsigned short* __restrict__ A, const unsigned short* __restrict__ Wt,
    const float* __restrict__ bq, const float* __restrict__ bk, const float* __restrict__ bv,
    unsigned short* __restrict__ qb, unsigned short* __restrict__ kb,
    unsigned short* __restrict__ vb, int M, int T)
{
    constexpr int K = D_MODEL;
    __shared__ unsigned short As[2][128 * 32];
    __shared__ unsigned short Bs[2][128 * 32];
    int t = threadIdx.x;
    int lane = t & 63, w = t >> 6;
    int ql = lane & 15, kg = lane >> 4;
    int m0 = blockIdx.y * 128, n0 = blockIdx.x * 128;
    int wm = w >> 2, wn = w & 3;
    bool vmode = (n0 >= 1024);

    const unsigned short* srcA = A + (size_t)(m0 + (t >> 2)) * K + (t & 3) * 8;
    const unsigned short* srcB = Wt + (size_t)(n0 + (t >> 2)) * K + (t & 3) * 8;

    f32x4 acc[4][2];
    #pragma unroll
    for (int i = 0; i < 4; i++)
        #pragma unroll
        for (int j = 0; j < 2; j++) { f32x4 z = {0.f, 0.f, 0.f, 0.f}; acc[i][j] = z; }

    constexpr int NIT = K / 32;
    int cur = 0;
    __builtin_amdgcn_global_load_lds((as1_uint*)(srcA),
        (as3_uint*)((char*)&As[0][0] + w * 1024), 16, 0, 0);
    __builtin_amdgcn_global_load_lds((as1_uint*)(srcB),
        (as3_uint*)((char*)&Bs[0][0] + w * 1024), 16, 0, 0);
    __syncthreads();

    for (int it = 0; it < NIT; ++it) {
        if (it + 1 < NIT) {
            int k0 = (it + 1) * 32;
            __builtin_amdgcn_global_load_lds((as1_uint*)(srcA + k0),
                (as3_uint*)((char*)&As[cur ^ 1][0] + w * 1024), 16, 0, 0);
            __builtin_amdgcn_global_load_lds((as1_uint*)(srcB + k0),
                (as3_uint*)((char*)&Bs[cur ^ 1][0] + w * 1024), 16, 0, 0);
        }
        short8 af[4], bfr[2];
        #pragma unroll
        for (int fm = 0; fm < 4; fm++)
            af[fm] = *(const short8*)((const char*)&As[cur][0] + (wm * 64 + fm * 16 + ql) * 64 + kg * 16);
        #pragma unroll
        for (int fn = 0; fn < 2; fn++)
            bfr[fn] = *(const short8*)((const char*)&Bs[cur][0] + (wn * 32 + fn * 16 + ql) * 64 + kg * 16);
        if (vmode) {
            #pragma unroll
            for (int fm = 0; fm < 4; fm++)
                #pragma unroll
                for (int fn = 0; fn < 2; fn++)
                    acc[fm][fn] = __builtin_amdgcn_mfma_f32_16x16x32_bf16(bfr[fn], af[fm], acc[fm][fn], 0, 0, 0);
        } else {
            #pragma unroll
            for (int fm = 0; fm < 4; fm++)
                #pragma unroll
                for (int fn = 0; fn < 2; fn++)
                    acc[fm][fn] = __builtin_amdgcn_mfma_f32_16x16x32_bf16(af[fm], bfr[fn], acc[fm][fn], 0, 0, 0);
        }
        __syncthreads();
        cur ^= 1;
    }

    #pragma unroll
    for (int fm = 0; fm < 4; fm++) {
        #pragma unroll
        for (int fn = 0; fn < 2; fn++) {
            if (vmode) {
                int m = m0 + wm * 64 + fm * 16 + ql;
                int b = m / T, tt = m % T;
                #pragma unroll
                for (int r = 0; r < 4; r++) {
                    int n = (n0 - 1024) + wn * 32 + fn * 16 + kg * 4 + r;
                    float val = acc[fm][fn][r] + bv[n];
                    int h = n >> 6, d = n & 63;
                    vb[((size_t)(b * N_HEADS + h) * DK + d) * T + tt] = f2bf(val);
                }
            } else {
                int n = n0 + wn * 32 + fn * 16 + ql;
                int nn = n & 511;
                bool isq = (n0 < 512);
                float bn = isq ? bq[nn] : bk[nn];
                unsigned short* dst = isq ? qb : kb;
                int h = nn >> 6, d = nn & 63;
                #pragma unroll
                for (int r = 0; r < 4; r++) {
                    int m = m0 + wm * 64 + fm * 16 + kg * 4 + r;
                    int b = m / T, tt = m % T;
                    float val = acc[fm][fn][r] + bn;
                    if (isq) val *= QSCALE;
                    dst[((size_t)(b * N_HEADS + h) * T + tt) * DK + d] = f2bf(val);
                }
            }
        }
    }
}

// ---------------- out-proj GEMM: fp32 out = attb @ Wo + bo ----------------
__global__ __launch_bounds__(512) void gemm_out_kernel(
    const unsigned short* __restrict__ A, const unsigned short* __restrict__ Bt,
    const float* __restrict__ bias, float* __restrict__ outp, int M)
{
    constexpr int K = D_MODEL;
    __shared__ unsigned short As[2][128 * 32];
    __shared__ unsigned short Bs[2][128 * 32];
    int t = threadIdx.x;
    int lane = t & 63, w = t >> 6;
    int ql = lane & 15, kg = lane >> 4;
    int m0 = blockIdx.y * 128, n0 = blockIdx.x * 128;
    int wm = w >> 2, wn = w & 3;

    const unsigned short* srcA = A + (size_t)(m0 + (t >> 2)) * K + (t & 3) * 8;
    const unsigned short* srcB = Bt + (size_t)(n0 + (t >> 2)) * K + (t & 3) * 8;

    f32x4 acc[4][2];
    #pragma unroll
    for (int i = 0; i < 4; i++)
        #pragma unroll
        for (int j = 0; j < 2; j++) { f32x4 z = {0.f, 0.f, 0.f, 0.f}; acc[i][j] = z; }

    constexpr int NIT = K / 32;
    int cur = 0;
    __builtin_amdgcn_global_load_lds((as1_uint*)(srcA),
        (as3_uint*)((char*)&As[0][0] + w * 1024), 16, 0, 0);
    __builtin_amdgcn_global_load_lds((as1_uint*)(srcB),
        (as3_uint*)((char*)&Bs[0][0] + w * 1024), 16, 0, 0);
    __syncthreads();

    for (int it = 0; it < NIT; ++it) {
        if (it + 1 < NIT) {
            int k0 = (it + 1) * 32;
            __builtin_amdgcn_global_load_lds((as1_uint*)(srcA + k0),
                (as3_uint*)((char*)&As[cur ^ 1][0] + w * 1024), 16, 0, 0);
            __builtin_amdgcn_global_load_lds((as1_uint*)(srcB + k0),
                (as3_uint*)((char*)&Bs[cur ^ 1][0] + w * 1024), 16, 0, 0);
        }
        short8 af[4], bfr[2];
        #pragma unroll
        for (int fm = 0; fm < 4; fm++)
            af[fm] = *(const short8*)((const char*)&As[cur][0] + (wm * 64 + fm * 16 + ql) * 64 + kg * 16);
        #pragma unroll
        for (int fn = 0; fn < 2; fn++)
            bfr[fn] = *(const short8*)((const char*)&Bs[cur][0] + (wn * 32 + fn * 16 + ql) * 64 + kg * 16);
        #pragma unroll
        for (int fm = 0; fm < 4; fm++)
            #pragma unroll
            for (int fn = 0; fn < 2; fn++)
                acc[fm][fn] = __builtin_amdgcn_mfma_f32_16x16x32_bf16(af[fm], bfr[fn], acc[fm][fn], 0, 0, 0);
        __syncthreads();
        cur ^= 1;
    }

    #pragma unroll
    for (int fm = 0; fm < 4; fm++) {
        #pragma unroll
        for (int fn = 0; fn < 2; fn++) {
            int n = n0 + wn * 32 + fn * 16 + ql;
            float bn = bias[n];
            #pragma unroll
            for (int r = 0; r < 4; r++) {
                int m = m0 + wm * 64 + fm * 16 + kg * 4 + r;
                outp[(size_t)m * D_MODEL + n] = acc[fm][fn][r] + bn;
            }
        }
    }
}

// ---------------- MFMA flash attention v11: pair-unrolled KV loop ----------------
// R9 structure (4 waves, QB=128, 32x32x16, in-register P) with KV tiles processed
// in independent PAIRS per barrier: Ks/Vt [2 pair-bufs][2 tiles] = 64KB, 2 blocks/CU.
// Tiles are fully independent (additive no-max softmax) -> cross-tile ILP.
__global__ __launch_bounds__(256) void attn_mfma_kernel(
    const unsigned short* __restrict__ q, const unsigned short* __restrict__ k,
    const unsigned short* __restrict__ v, const unsigned char* __restrict__ mu,
    unsigned short* __restrict__ out, int B, int T)
{
    __shared__ unsigned short Ks[2][2][64 * 64];
    __shared__ unsigned short Vt[2][2][64 * 64];

    int t = threadIdx.x;
    int lane = t & 63, w = t >> 6;
    int ln = lane & 31, hi = lane >> 5;
    int bh = blockIdx.x;
    int qt = blockIdx.y;
    int hh = bh & (N_HEADS - 1), b = bh >> 3;
    int qr0 = qt * 128;

    const char* kbase = (const char*)(k + (size_t)bh * T * DK);
    const char* vbase = (const char*)(v + (size_t)bh * DK * T);

    // staging addresses: LDS linear dest, inverse-swizzled global source
    int lin0 = w * 1024 + lane * 16;
    int lin1 = 4096 + lin0;
    int row0 = lin0 >> 7, row1 = lin1 >> 7;
    int sw0 = (row0 & 7) << 4, sw1 = (row1 & 7) << 4;
    const char* gK0 = kbase + (lin0 ^ sw0);
    const char* gK1 = kbase + (lin1 ^ sw1);
    const char* gV0 = vbase + (size_t)row0 * (2 * T) + ((lin0 & 127) ^ sw0);
    const char* gV1 = vbase + (size_t)row1 * (2 * T) + ((lin1 & 127) ^ sw1);

    // Q B-fragments: lane holds Q[q = qr0 + w*32 + ln][ks*16 + hi*8 .. +7]
    short8 qfr[4];
    {
        const unsigned short* qrow = q + ((size_t)bh * T + qr0 + w * 32 + ln) * DK + hi * 8;
        #pragma unroll
        for (int ks = 0; ks < 4; ks++)
            qfr[ks] = *(const short8*)(qrow + ks * 16);
    }

    // mask: lane's q-row, strided dwords (kcol = rb*32 + g*8 + 4*hi + 0..3)
    const unsigned char* mbase = mu + (size_t)(qr0 + w * 32 + ln) * T + 4 * hi;

    f32x16 oacc[2];
    #pragma unroll
    for (int db = 0; db < 2; db++)
        #pragma unroll
        for (int i = 0; i < 16; i++) oacc[db][i] = 0.f;
    float lacc = 0.f;

    // prologue: mask pair 0 + stage K/V pair 0 -> buf 0
    unsigned mcur[2][8];
    #pragma unroll
    for (int s = 0; s < 2; s++)
        #pragma unroll
        for (int rb = 0; rb < 2; rb++)
            #pragma unroll
            for (int g = 0; g < 4; g++)
                mcur[s][rb * 4 + g] = *(const unsigned*)(mbase + s * 64 + rb * 32 + g * 8);
    #pragma unroll
    for (int s = 0; s < 2; s++) {
        __builtin_amdgcn_global_load_lds((as1_uint*)(gK0 + (size_t)s * 8192),
            (as3_uint*)((char*)&Ks[0][s][0] + lin0), 16, 0, 0);
        __builtin_amdgcn_global_load_lds((as1_uint*)(gK1 + (size_t)s * 8192),
            (as3_uint*)((char*)&Ks[0][s][0] + lin1), 16, 0, 0);
        __builtin_amdgcn_global_load_lds((as1_uint*)(gV0 + (size_t)s * 128),
            (as3_uint*)((char*)&Vt[0][s][0] + lin0), 16, 0, 0);
        __builtin_amdgcn_global_load_lds((as1_uint*)(gV1 + (size_t)s * 128),
            (as3_uint*)((char*)&Vt[0][s][0] + lin1), 16, 0, 0);
    }

    int npairs = T / 128;
    for (int j = 0; j < npairs; j++) {
        __syncthreads();   // pair buf[cur] staged (vmcnt drained); prev reads done
        int cur = j & 1;
        bool havenext = (j + 1) < npairs;

        unsigned mnxt[2][8];
        if (havenext) {
            #pragma unroll
            for (int s = 0; s < 2; s++) {
                const unsigned char* mp = mbase + (size_t)(2 * (j + 1) + s) * 64;
                #pragma unroll
                for (int rb = 0; rb < 2; rb++)
                    #pragma unroll
                    for (int g = 0; g < 4; g++)
                        mnxt[s][rb * 4 + g] = *(const unsigned*)(mp + rb * 32 + g * 8);
            }
            size_t ko = (size_t)(2 * (j + 1)) * 8192;
            size_t vo = (size_t)(2 * (j + 1)) * 128;
            #pragma unroll
            for (int s = 0; s < 2; s++) {
                __builtin_amdgcn_global_load_lds((as1_uint*)(gK0 + ko + (size_t)s * 8192),
                    (as3_uint*)((char*)&Ks[cur ^ 1][s][0] + lin0), 16, 0, 0);
                __builtin_amdgcn_global_load_lds((as1_uint*)(gK1 + ko + (size_t)s * 8192),
                    (as3_uint*)((char*)&Ks[cur ^ 1][s][0] + lin1), 16, 0, 0);
                __builtin_amdgcn_global_load_lds((as1_uint*)(gV0 + vo + (size_t)s * 128),
                    (as3_uint*)((char*)&Vt[cur ^ 1][s][0] + lin0), 16, 0, 0);
                __builtin_amdgcn_global_load_lds((as1_uint*)(gV1 + vo + (size_t)s * 128),
                    (as3_uint*)((char*)&Vt[cur ^ 1][s][0] + lin1), 16, 0, 0);
            }
        }

        // two INDEPENDENT tiles; unrolled into one scheduling region
        #pragma unroll
        for (int s = 0; s < 2; s++) {
            // QK^T (swapped): sacc[rb][reg] = S[kcol = rb*32+(reg&3)+8*(reg>>2)+4*hi][q=ln]
            f32x16 sacc[2];
            #pragma unroll
            for (int rb = 0; rb < 2; rb++)
                #pragma unroll
                for (int i = 0; i < 16; i++) sacc[rb][i] = 0.f;
            __builtin_amdgcn_s_setprio(1);
            #pragma unroll
            for (int ks = 0; ks < 4; ks++) {
                #pragma unroll
                for (int rb = 0; rb < 2; rb++) {
                    int row = rb * 32 + ln;
                    short8 kf = *(const short8*)((const char*)&Ks[cur][s][0] +
                                ((row * 128 + ks * 32 + hi * 16) ^ ((row & 7) << 4)));
                    sacc[rb] = __builtin_amdgcn_mfma_f32_32x32x16_bf16(kf, qfr[ks], sacc[rb], 0, 0, 0);
                }
            }
            __builtin_amdgcn_s_setprio(0);

            // softmax: p = exp2(s*m); PV A-frags in-register (cvt_pk + permlane32_swap)
            short8 pa[4];
            #pragma unroll
            for (int rb = 0; rb < 2; rb++) {
                float p[16];
                #pragma unroll
                for (int g = 0; g < 4; g++) {
                    unsigned mw = mcur[s][rb * 4 + g];
                    float p0 = __builtin_amdgcn_exp2f(sacc[rb][g * 4 + 0] * (float)(mw & 0xffu));
                    float p1 = __builtin_amdgcn_exp2f(sacc[rb][g * 4 + 1] * (float)((mw >> 8) & 0xffu));
                    float p2 = __builtin_amdgcn_exp2f(sacc[rb][g * 4 + 2] * (float)((mw >> 16) & 0xffu));
                    float p3 = __builtin_amdgcn_exp2f(sacc[rb][g * 4 + 3] * (float)(mw >> 24));
                    p[g * 4 + 0] = p0; p[g * 4 + 1] = p1; p[g * 4 + 2] = p2; p[g * 4 + 3] = p3;
                    lacc += (p0 + p1) + (p2 + p3);
                }
                #pragma unroll
                for (int kl = 0; kl < 2; kl++) {
                    int b0 = kl * 8;
                    unsigned d0, d1, d2, d3;
                    asm("v_cvt_pk_bf16_f32 %0, %1, %2" : "=v"(d0) : "v"(p[b0 + 0]), "v"(p[b0 + 1]));
                    asm("v_cvt_pk_bf16_f32 %0, %1, %2" : "=v"(d1) : "v"(p[b0 + 2]), "v"(p[b0 + 3]));
                    asm("v_cvt_pk_bf16_f32 %0, %1, %2" : "=v"(d2) : "v"(p[b0 + 4]), "v"(p[b0 + 5]));
                    asm("v_cvt_pk_bf16_f32 %0, %1, %2" : "=v"(d3) : "v"(p[b0 + 6]), "v"(p[b0 + 7]));
                    asm("v_permlane32_swap_b32 %0, %1" : "+v"(d0), "+v"(d2));
                    asm("v_permlane32_swap_b32 %0, %1" : "+v"(d1), "+v"(d3));
                    uint4 fr = { d0, d1, d2, d3 };
                    pa[rb * 2 + kl] = __builtin_bit_cast(short8, fr);
                }
            }

            // PV: oacc[db] += P(32q x 64k) @ V(64k x [db*32..+31])
            __builtin_amdgcn_s_setprio(1);
            #pragma unroll
            for (int ks = 0; ks < 4; ks++) {
                #pragma unroll
                for (int db = 0; db < 2; db++) {
                    int row = db * 32 + ln;
                    short8 vb = *(const short8*)((const char*)&Vt[cur][s][0] +
                                ((row * 128 + ks * 32 + hi * 16) ^ ((row & 7) << 4)));
                    oacc[db] = __builtin_amdgcn_mfma_f32_32x32x16_bf16(pa[ks], vb, oacc[db], 0, 0, 0);
                }
            }
            __builtin_amdgcn_s_setprio(0);
        }

        if (havenext) {
            #pragma unroll
            for (int s = 0; s < 2; s++)
                #pragma unroll
                for (int c = 0; c < 8; c++) mcur[s][c] = mnxt[s][c];
        }
    }

    // l: lane owns q=ln; other half of kcols sits at lane^32
    lacc += __shfl_xor(lacc, 32, 64);

    // store: oacc[db][reg] is O[q = (reg&3)+8*(reg>>2)+4*hi][d = db*32 + ln]
    #pragma unroll
    for (int reg = 0; reg < 16; reg++) {
        int qoff = (reg & 3) + 8 * (reg >> 2) + 4 * hi;
        float linv = 1.0f / __shfl(lacc, qoff, 64);
        size_t rowo = ((size_t)b * T + qr0 + w * 32 + qoff) * D_MODEL + hh * DK + ln;
        out[rowo]      = f2bf(oacc[0][reg] * linv);
        out[rowo + 32] = f2bf(oacc[1][reg] * linv);
    }
}

extern "C" void kernel_launch(void* const* d_in, const int* in_sizes, int n_in,
                              void* d_out, int out_size, void* d_ws, size_t ws_size,
                              hipStream_t stream) {
    const float* x    = (const float*)d_in[0];
    const float* mask = (const float*)d_in[1];
    const float* Wq   = (const float*)d_in[2];
    const float* bq   = (const float*)d_in[3];
    const float* Wk   = (const float*)d_in[4];
    const float* bk   = (const float*)d_in[5];
    const float* Wv   = (const float*)d_in[6];
    const float* bv   = (const float*)d_in[7];
    const float* Wo   = (const float*)d_in[8];
    const float* bo   = (const float*)d_in[9];

    int T = (int)(sqrt((double)in_sizes[1]) + 0.5);   // 4096
    int C = D_MODEL;
    int B = in_sizes[0] / (T * C);                    // 2
    int M = B * T;

    size_t MK = (size_t)M * C;
    unsigned short* xb  = (unsigned short*)d_ws;
    unsigned short* Wtq = xb + MK;                    // [2048][512]: q,k,v,o contiguous
    unsigned short* Wto = Wtq + 3 * (size_t)C * C;
    unsigned short* qb  = Wtq + 4 * (size_t)C * C;
    unsigned short* kb  = qb + MK;
    unsigned short* vb  = kb + MK;
    unsigned short* attb = vb + MK;
    unsigned char*  mu  = (unsigned char*)(attb + MK);

    int n8 = (int)(MK / 8);
    cvt_x_kernel<<<(n8 + 255) / 256, 256, 0, stream>>>(x, xb, n8);
    int n4 = T * T / 4;
    cvt_mask_kernel<<<(n4 + 255) / 256, 256, 0, stream>>>(mask, mu, n4);
    dim3 wtg(C / 64, C / 64, 4);
    cvt_wt4_kernel<<<wtg, 256, 0, stream>>>(Wq, Wk, Wv, Wo, Wtq);

    dim3 gq(3 * C / 128, M / 128, 1);
    gemm_qkv_kernel<<<gq, 512, 0, stream>>>(xb, Wtq, bq, bk, bv, qb, kb, vb, M, T);

    dim3 ga(B * N_HEADS, T / 128, 1);
    attn_mfma_kernel<<<ga, 256, 0, stream>>>(qb, kb, vb, mu, attb, B, T);

    dim3 gg(C / 128, M / 128, 1);
    gemm_out_kernel<<<gg, 512, 0, stream>>>(attb, Wto, bo, (float*)d_out, M);
}